// Round 2
// baseline (198.045 us; speedup 1.0000x reference)
//
#include <hip/hip_runtime.h>
#include <hip/hip_bf16.h>

// Problem: B=256, T=256, C=384, H=64, MAX_REL=3 (causal -> rel idx 0..3 only)
// Round 9: r8 fused kernel was latency-bound (78 us, all pipes <15%, 2 waves/SIMD,
// VGPR spill evident from WRITE_SIZE). This round: 1024 threads / 16 waves per
// block (4 waves/SIMD -> 2x TLP), halved per-wave register pressure (no spill),
// and phase-2 work split across wave PAIRS:
//   - scores: pair (w, w+8) handles q-tiles {p,15-p}; s-tiles split by parity
//     (balanced ~9 score-tiles/wave vs 17 before)
//   - row-sum l exchanged via small LDS buffer + block barrier
//   - PV + epilogue split by nt columns (each wave owns 2 of 4 h-tiles; no
//     cross-wave O reduction needed)
// Phase 1: each wave owns 16 rows; W staged in 3 x 48 KB LDS chunks; x chunk
// prefetched into single-buffered regs (tmp[8]) during previous chunk's MFMAs.

typedef __attribute__((ext_vector_type(8))) __bf16 bf16x8;
typedef __attribute__((ext_vector_type(8))) short short8;
typedef __attribute__((ext_vector_type(4))) float f32x4;
typedef __attribute__((ext_vector_type(4))) int   i32x4;

#define MFMA16(A, B, C) __builtin_amdgcn_mfma_f32_16x16x32_bf16((A), (B), (C), 0, 0, 0)

__device__ __forceinline__ unsigned short f2bf(float f) {
    unsigned int u = __builtin_bit_cast(unsigned int, f);
    u = (u + 0x7FFFu + ((u >> 16) & 1u)) >> 16;   // RNE
    return (unsigned short)u;
}
__device__ __forceinline__ float bf2f(unsigned short s) {
    unsigned int u = ((unsigned int)s) << 16;
    return __builtin_bit_cast(float, u);
}
__device__ __forceinline__ bf16x8 ld16(const unsigned short* p) {
    return __builtin_bit_cast(bf16x8, *(const i32x4*)p);
}

// ---------------------------------------------------------------------------
// Kernel 0: Wt[3][64][384] bf16 (W^T) + Rk[16][64] bf16 (rel_k rows 0..3, rest 0)
// ---------------------------------------------------------------------------
__global__ void prep_wt(const float* __restrict__ Wq, const float* __restrict__ Wk,
                        const float* __restrict__ Wv, const float* __restrict__ relk,
                        unsigned short* __restrict__ Wt, unsigned short* __restrict__ Rk) {
    int i = blockIdx.x * 256 + threadIdx.x;
    if (i < 3 * 64 * 384) {
        int kk = i % 384;
        int h  = (i / 384) & 63;
        int w  = i / (384 * 64);
        const float* W = (w == 0) ? Wq : ((w == 1) ? Wk : Wv);
        Wt[i] = f2bf(W[kk * 64 + h]);
    } else if (i < 3 * 64 * 384 + 1024) {
        int j = i - 3 * 64 * 384;
        int n = j >> 6, h = j & 63;
        Rk[j] = (n < 4) ? f2bf(relk[n * 64 + h]) : (unsigned short)0;
    }
}

// ---------------------------------------------------------------------------
// Fused QKV + attention. One block per batch, 1024 threads (16 waves).
// LDS layout (u16 offsets; total 79872 u16 = 159744 B):
//   ksh [256][72]  @ 0       36864 B   persistent
//   vTs [64][264]  @ 18432   33792 B   persistent
//   qs  [256][72]  @ 35328   36864 B   freed after q-frag loads \  P region
//   wc  [192][136] @ 53760   52224 B   freed after phase 1      /  8x[16][264]
//   P(pair p) = 35328 + p*4224 ; lsum (8x2x16 f32) @ u16 69120
// Row strides 72/136/264 u16 are 4 dwords mod 32 banks -> only free 2-way
// aliasing on 16-lane b128 column accesses.
// ---------------------------------------------------------------------------
__global__ __launch_bounds__(1024, 1) void fused_kernel(
        const float* __restrict__ x, const unsigned short* __restrict__ Wt,
        const unsigned short* __restrict__ Rk, const float* __restrict__ relv,
        float* __restrict__ out) {
    extern __shared__ unsigned short sh[];
    unsigned short* ksh = sh;
    unsigned short* vTs = sh + 18432;
    unsigned short* qs  = sh + 35328;
    unsigned short* wc  = sh + 53760;
    float* lsum = (float*)(sh + 69120);

    const int tid  = threadIdx.x;
    const int wave = tid >> 6;
    const int lane = tid & 63;
    const int c    = lane & 15;
    const int quad = lane >> 4;
    const int b    = blockIdx.x;

    const f32x4 zero = {0.f, 0.f, 0.f, 0.f};

    // =================== phase 1: QKV GEMM into LDS ===================
    // wave owns rows wave*16 + c ; lane reads its row at cols quad*8..+7 per j
    const float* xbase = x + (size_t)(b * 256 + wave * 16 + c) * 384 + quad * 8;

    f32x4 aq[4], ak[4], av[4];
#pragma unroll
    for (int nt = 0; nt < 4; nt++) { aq[nt] = zero; ak[nt] = zero; av[nt] = zero; }

    // prologue: issue x loads for chunk 0
    f32x4 tmp[8];
#pragma unroll
    for (int j = 0; j < 4; j++) {
        tmp[2 * j]     = *(const f32x4*)(xbase + j * 32);
        tmp[2 * j + 1] = *(const f32x4*)(xbase + j * 32 + 4);
    }

#pragma unroll
    for (int ck = 0; ck < 3; ck++) {
        if (ck) __syncthreads();               // all waves done reading wc(ck-1)
        // stage W chunk ck: 192 rows x 128 u16 = 3072 b128 pieces, 3/thread
#pragma unroll
        for (int it = 0; it < 3; it++) {
            int P_ = it * 1024 + tid;
            int r = P_ >> 4, pc = P_ & 15;
            i32x4 d = *(const i32x4*)(Wt + r * 384 + ck * 128 + pc * 8);
            *(i32x4*)(wc + r * 136 + pc * 8) = d;
        }
        __syncthreads();                       // wc ready (x loads retired too)

        // convert this chunk's x to bf16 A-frags (frees tmp for the prefetch)
        bf16x8 a[4];
#pragma unroll
        for (int j = 0; j < 4; j++) {
            short8 xs8;
#pragma unroll
            for (int e = 0; e < 4; e++) {
                xs8[e]     = (short)f2bf(tmp[2 * j][e]);
                xs8[4 + e] = (short)f2bf(tmp[2 * j + 1][e]);
            }
            a[j] = __builtin_bit_cast(bf16x8, xs8);
        }
        // prefetch next chunk's x; lands during the MFMA loop below
        if (ck < 2) {
#pragma unroll
            for (int j = 0; j < 4; j++) {
                const float* xp = xbase + (ck + 1) * 128 + j * 32;
                tmp[2 * j]     = *(const f32x4*)xp;
                tmp[2 * j + 1] = *(const f32x4*)(xp + 4);
            }
        }

#pragma unroll
        for (int j = 0; j < 4; j++) {
            const int col = j * 32 + quad * 8;
#pragma unroll
            for (int nt = 0; nt < 4; nt++) {
                bf16x8 bq = ld16(wc + (nt * 16 + c) * 136 + col);
                bf16x8 bk = ld16(wc + (64 + nt * 16 + c) * 136 + col);
                bf16x8 aw = ld16(wc + (128 + nt * 16 + c) * 136 + col);
                aq[nt] = MFMA16(a[j], bq, aq[nt]);   // D[t][h]
                ak[nt] = MFMA16(a[j], bk, ak[nt]);   // D[t][h]
                av[nt] = MFMA16(aw, a[j], av[nt]);   // D[h][t]
            }
        }
    }

    // epilogue into LDS (C/D layout: col=lane&15, row=quad*4+reg)
#pragma unroll
    for (int nt = 0; nt < 4; nt++)
#pragma unroll
        for (int r = 0; r < 4; r++) {
            int row = wave * 16 + quad * 4 + r;
            qs[row * 72 + nt * 16 + c]  = f2bf(aq[nt][r]);
            ksh[row * 72 + nt * 16 + c] = f2bf(ak[nt][r]);
            vTs[(nt * 16 + quad * 4 + r) * 264 + wave * 16 + c] = f2bf(av[nt][r]);
        }
    __syncthreads();                           // q/k/vT visible to all waves

    // =================== phase 2: attention from LDS ===================
    // pair p = wave&7 handles q-tiles {p, 15-p}; hi = wave>>3 is the pair half.
    // scores split by s-tile parity; PV + output split by nt (2 per wave).
    const int p  = wave & 7;
    const int hi = wave >> 3;
    const int tA = p, tB = 15 - p;

    bf16x8 qA0 = ld16(qs + (tA * 16 + c) * 72 + quad * 8);
    bf16x8 qA1 = ld16(qs + (tA * 16 + c) * 72 + 32 + quad * 8);
    bf16x8 qB0 = ld16(qs + (tB * 16 + c) * 72 + quad * 8);
    bf16x8 qB1 = ld16(qs + (tB * 16 + c) * 72 + 32 + quad * 8);
    float rv[4][2];
#pragma unroll
    for (int j = 0; j < 4; j++)
#pragma unroll
        for (int i = 0; i < 2; i++)
            rv[j][i] = relv[j * 64 + (hi * 2 + i) * 16 + c];
    __syncthreads();                           // qs reads done -> P may overwrite

    unsigned short* Pw = sh + 35328 + p * 4224;    // per-PAIR [16][264]

#pragma unroll
    for (int it2 = 0; it2 < 2; it2++) {
        const int tt  = it2 ? tB : tA;
        const bf16x8 aq0 = it2 ? qB0 : qA0;
        const bf16x8 aq1 = it2 ? qB1 : qA1;
        const int nst = tt + 1;

        // E via MFMA vs Rk: D[m=quad*4+r][n=c] = q_{t0+m} . relk_n  (n<4 valid)
        f32x4 e = zero;
        e = MFMA16(aq0, ld16(Rk + c * 64 + quad * 8), e);
        e = MFMA16(aq1, ld16(Rk + c * 64 + 32 + quad * 8), e);
        float ef[4][4];
#pragma unroll
        for (int r = 0; r < 4; r++)
#pragma unroll
            for (int n = 0; n < 4; n++)
                ef[r][n] = __shfl(e[r], (lane & 48) + n, 64);

        // score tiles of my parity -> exp -> P^ in LDS; partial row sums
        float l[4] = {0.f, 0.f, 0.f, 0.f};
#pragma unroll
        for (int st = 0; st < 16; st++) {
            if ((st & 1) == hi) {
                if (st < nst) {
                    const unsigned short* kp = ksh + (st * 16 + c) * 72 + quad * 8;
                    f32x4 s = zero;
                    s = MFMA16(aq0, ld16(kp), s);
                    s = MFMA16(aq1, ld16(kp + 32), s);
#pragma unroll
                    for (int r = 0; r < 4; r++) {
                        int tg = tt * 16 + quad * 4 + r;
                        int sg = st * 16 + c;
                        int d  = sg - tg;
                        float ee = (d <= -3) ? ef[r][0] : (d == -2) ? ef[r][1]
                                 : (d == -1) ? ef[r][2] : ef[r][3];
                        float pv = (d > 0) ? 0.f : __expf(0.125f * (s[r] + ee));
                        l[r] += pv;
                        Pw[(quad * 4 + r) * 264 + sg] = f2bf(pv);
                    }
                } else if (st == nst && (nst & 1)) {
                    // zero-pad the half-open MFMA k-tile (odd nst -> parity 1)
#pragma unroll
                    for (int r = 0; r < 4; r++)
                        Pw[(quad * 4 + r) * 264 + st * 16 + c] = 0;
                }
            }
        }
        // partial row-sum over the 16 c-lanes, then exchange across the pair
#pragma unroll
        for (int r = 0; r < 4; r++)
#pragma unroll
            for (int ofs = 1; ofs < 16; ofs <<= 1)
                l[r] += __shfl_xor(l[r], ofs, 64);
        if (c == 0) {
#pragma unroll
            for (int r = 0; r < 4; r++)
                lsum[(p * 2 + hi) * 16 + quad * 4 + r] = l[r];
        }
        __syncthreads();                       // lsum + partner's P^ visible
        float rl[4];
#pragma unroll
        for (int r = 0; r < 4; r++)
            rl[r] = 1.0f / (l[r] + lsum[(p * 2 + (1 - hi)) * 16 + quad * 4 + r]);

        // O = P^ @ V  for my 2 nt columns (A rows m=c from P; B = vT from LDS)
        f32x4 o[2];
        o[0] = zero; o[1] = zero;
        const int ksteps = (nst + 1) >> 1;
#pragma unroll
        for (int ks = 0; ks < 8; ks++) {
            if (ks < ksteps) {
                bf16x8 ap = ld16(Pw + c * 264 + ks * 32 + quad * 8);
#pragma unroll
                for (int i = 0; i < 2; i++) {
                    const int nt = hi * 2 + i;
                    bf16x8 bv = ld16(vTs + (nt * 16 + c) * 264 + ks * 32 + quad * 8);
                    o[i] = MFMA16(ap, bv, o[i]);
                }
            }
        }

        // epilogue: normalize + w2 band-probability identity + store my 2 nt
#pragma unroll
        for (int r = 0; r < 4; r++) {
            int tl = quad * 4 + r;
            int tg = tt * 16 + tl;
            float pa  = (tg >= 2) ? bf2f(Pw[tl * 264 + tg - 2]) * rl[r] : 0.f;
            float pb  = (tg >= 1) ? bf2f(Pw[tl * 264 + tg - 1]) * rl[r] : 0.f;
            float pcv = bf2f(Pw[tl * 264 + tg]) * rl[r];
#pragma unroll
            for (int i = 0; i < 2; i++) {
                const int nt = hi * 2 + i;
                float r0 = rv[0][i];
                float w2 = r0 + pa * (rv[1][i] - r0) + pb * (rv[2][i] - r0)
                              + pcv * (rv[3][i] - r0);
                out[(size_t)(b * 256 + tg) * 64 + nt * 16 + c] = o[i][r] * rl[r] + w2;
            }
        }
        __syncthreads();                       // P^/lsum reads done before reuse
    }
}

// ---------------------------------------------------------------------------
extern "C" void kernel_launch(void* const* d_in, const int* in_sizes, int n_in,
                              void* d_out, int out_size, void* d_ws, size_t ws_size,
                              hipStream_t stream) {
    const float* x    = (const float*)d_in[0];
    const float* Wq   = (const float*)d_in[1];
    const float* Wk   = (const float*)d_in[2];
    const float* Wv   = (const float*)d_in[3];
    const float* relk = (const float*)d_in[4];
    const float* relv = (const float*)d_in[5];
    float* out = (float*)d_out;

    char* ws = (char*)d_ws;
    unsigned short* Wt = (unsigned short*)(ws);              // 147456 B
    unsigned short* Rk = (unsigned short*)(ws + 147456);     // 2048 B

    (void)hipFuncSetAttribute((const void*)fused_kernel,
                              hipFuncAttributeMaxDynamicSharedMemorySize, 159744);

    prep_wt<<<292, 256, 0, stream>>>(Wq, Wk, Wv, relk, Wt, Rk);
    fused_kernel<<<256, 1024, 159744, stream>>>(x, Wt, Rk, relv, out);
}

// Round 3
// 196.538 us; speedup vs baseline: 1.0077x; 1.0077x over previous
//
#include <hip/hip_runtime.h>
#include <hip/hip_bf16.h>

// Problem: B=256, T=256, C=384, H=64, MAX_REL=3 (causal -> rel idx 0..3 only)
// Round 10: r9 structure was sound but the compiler allocated 64 VGPR
// (targeting 8 waves/SIMD that LDS=156KB can never deliver) and spilled the
// ~110-VGPR phase-1 working set -> 26 MB scratch writes (WRITE_SIZE 42.8 MB vs
// 16.8 MB output), scratch-latency-bound at 78 us regardless of occupancy.
// Single change: amdgpu_waves_per_eu(4,4) pins the allocator budget to
// 512/4 = 128 VGPR (the occupancy we actually run at: 16 waves, 1 block/CU).
// Everything else is r9 verbatim.

typedef __attribute__((ext_vector_type(8))) __bf16 bf16x8;
typedef __attribute__((ext_vector_type(8))) short short8;
typedef __attribute__((ext_vector_type(4))) float f32x4;
typedef __attribute__((ext_vector_type(4))) int   i32x4;

#define MFMA16(A, B, C) __builtin_amdgcn_mfma_f32_16x16x32_bf16((A), (B), (C), 0, 0, 0)

__device__ __forceinline__ unsigned short f2bf(float f) {
    unsigned int u = __builtin_bit_cast(unsigned int, f);
    u = (u + 0x7FFFu + ((u >> 16) & 1u)) >> 16;   // RNE
    return (unsigned short)u;
}
__device__ __forceinline__ float bf2f(unsigned short s) {
    unsigned int u = ((unsigned int)s) << 16;
    return __builtin_bit_cast(float, u);
}
__device__ __forceinline__ bf16x8 ld16(const unsigned short* p) {
    return __builtin_bit_cast(bf16x8, *(const i32x4*)p);
}

// ---------------------------------------------------------------------------
// Kernel 0: Wt[3][64][384] bf16 (W^T) + Rk[16][64] bf16 (rel_k rows 0..3, rest 0)
// ---------------------------------------------------------------------------
__global__ void prep_wt(const float* __restrict__ Wq, const float* __restrict__ Wk,
                        const float* __restrict__ Wv, const float* __restrict__ relk,
                        unsigned short* __restrict__ Wt, unsigned short* __restrict__ Rk) {
    int i = blockIdx.x * 256 + threadIdx.x;
    if (i < 3 * 64 * 384) {
        int kk = i % 384;
        int h  = (i / 384) & 63;
        int w  = i / (384 * 64);
        const float* W = (w == 0) ? Wq : ((w == 1) ? Wk : Wv);
        Wt[i] = f2bf(W[kk * 64 + h]);
    } else if (i < 3 * 64 * 384 + 1024) {
        int j = i - 3 * 64 * 384;
        int n = j >> 6, h = j & 63;
        Rk[j] = (n < 4) ? f2bf(relk[n * 64 + h]) : (unsigned short)0;
    }
}

// ---------------------------------------------------------------------------
// Fused QKV + attention. One block per batch, 1024 threads (16 waves).
// LDS layout (u16 offsets; total 79872 u16 = 159744 B):
//   ksh [256][72]  @ 0       36864 B   persistent
//   vTs [64][264]  @ 18432   33792 B   persistent
//   qs  [256][72]  @ 35328   36864 B   freed after q-frag loads \  P region
//   wc  [192][136] @ 53760   52224 B   freed after phase 1      /  8x[16][264]
//   P(pair p) = 35328 + p*4224 ; lsum (8x2x16 f32) @ u16 69120
// ---------------------------------------------------------------------------
__global__ __launch_bounds__(1024)
__attribute__((amdgpu_waves_per_eu(4, 4)))
void fused_kernel(
        const float* __restrict__ x, const unsigned short* __restrict__ Wt,
        const unsigned short* __restrict__ Rk, const float* __restrict__ relv,
        float* __restrict__ out) {
    extern __shared__ unsigned short sh[];
    unsigned short* ksh = sh;
    unsigned short* vTs = sh + 18432;
    unsigned short* qs  = sh + 35328;
    unsigned short* wc  = sh + 53760;
    float* lsum = (float*)(sh + 69120);

    const int tid  = threadIdx.x;
    const int wave = tid >> 6;
    const int lane = tid & 63;
    const int c    = lane & 15;
    const int quad = lane >> 4;
    const int b    = blockIdx.x;

    const f32x4 zero = {0.f, 0.f, 0.f, 0.f};

    // =================== phase 1: QKV GEMM into LDS ===================
    // wave owns rows wave*16 + c ; lane reads its row at cols quad*8..+7 per j
    const float* xbase = x + (size_t)(b * 256 + wave * 16 + c) * 384 + quad * 8;

    f32x4 aq[4], ak[4], av[4];
#pragma unroll
    for (int nt = 0; nt < 4; nt++) { aq[nt] = zero; ak[nt] = zero; av[nt] = zero; }

    // prologue: issue x loads for chunk 0
    f32x4 tmp[8];
#pragma unroll
    for (int j = 0; j < 4; j++) {
        tmp[2 * j]     = *(const f32x4*)(xbase + j * 32);
        tmp[2 * j + 1] = *(const f32x4*)(xbase + j * 32 + 4);
    }

#pragma unroll
    for (int ck = 0; ck < 3; ck++) {
        if (ck) __syncthreads();               // all waves done reading wc(ck-1)
        // stage W chunk ck: 192 rows x 128 u16 = 3072 b128 pieces, 3/thread
#pragma unroll
        for (int it = 0; it < 3; it++) {
            int P_ = it * 1024 + tid;
            int r = P_ >> 4, pc = P_ & 15;
            i32x4 d = *(const i32x4*)(Wt + r * 384 + ck * 128 + pc * 8);
            *(i32x4*)(wc + r * 136 + pc * 8) = d;
        }
        __syncthreads();                       // wc ready (x loads retired too)

        // convert this chunk's x to bf16 A-frags (frees tmp for the prefetch)
        bf16x8 a[4];
#pragma unroll
        for (int j = 0; j < 4; j++) {
            short8 xs8;
#pragma unroll
            for (int e = 0; e < 4; e++) {
                xs8[e]     = (short)f2bf(tmp[2 * j][e]);
                xs8[4 + e] = (short)f2bf(tmp[2 * j + 1][e]);
            }
            a[j] = __builtin_bit_cast(bf16x8, xs8);
        }
        // prefetch next chunk's x; lands during the MFMA loop below
        if (ck < 2) {
#pragma unroll
            for (int j = 0; j < 4; j++) {
                const float* xp = xbase + (ck + 1) * 128 + j * 32;
                tmp[2 * j]     = *(const f32x4*)xp;
                tmp[2 * j + 1] = *(const f32x4*)(xp + 4);
            }
        }

#pragma unroll
        for (int j = 0; j < 4; j++) {
            const int col = j * 32 + quad * 8;
#pragma unroll
            for (int nt = 0; nt < 4; nt++) {
                bf16x8 bq = ld16(wc + (nt * 16 + c) * 136 + col);
                bf16x8 bk = ld16(wc + (64 + nt * 16 + c) * 136 + col);
                bf16x8 aw = ld16(wc + (128 + nt * 16 + c) * 136 + col);
                aq[nt] = MFMA16(a[j], bq, aq[nt]);   // D[t][h]
                ak[nt] = MFMA16(a[j], bk, ak[nt]);   // D[t][h]
                av[nt] = MFMA16(aw, a[j], av[nt]);   // D[h][t]
            }
        }
    }

    // epilogue into LDS (C/D layout: col=lane&15, row=quad*4+reg)
#pragma unroll
    for (int nt = 0; nt < 4; nt++)
#pragma unroll
        for (int r = 0; r < 4; r++) {
            int row = wave * 16 + quad * 4 + r;
            qs[row * 72 + nt * 16 + c]  = f2bf(aq[nt][r]);
            ksh[row * 72 + nt * 16 + c] = f2bf(ak[nt][r]);
            vTs[(nt * 16 + quad * 4 + r) * 264 + wave * 16 + c] = f2bf(av[nt][r]);
        }
    __syncthreads();                           // q/k/vT visible to all waves

    // =================== phase 2: attention from LDS ===================
    // pair p = wave&7 handles q-tiles {p, 15-p}; hi = wave>>3 is the pair half.
    // scores split by s-tile parity; PV + output split by nt (2 per wave).
    const int p  = wave & 7;
    const int hi = wave >> 3;
    const int tA = p, tB = 15 - p;

    bf16x8 qA0 = ld16(qs + (tA * 16 + c) * 72 + quad * 8);
    bf16x8 qA1 = ld16(qs + (tA * 16 + c) * 72 + 32 + quad * 8);
    bf16x8 qB0 = ld16(qs + (tB * 16 + c) * 72 + quad * 8);
    bf16x8 qB1 = ld16(qs + (tB * 16 + c) * 72 + 32 + quad * 8);
    float rv[4][2];
#pragma unroll
    for (int j = 0; j < 4; j++)
#pragma unroll
        for (int i = 0; i < 2; i++)
            rv[j][i] = relv[j * 64 + (hi * 2 + i) * 16 + c];
    __syncthreads();                           // qs reads done -> P may overwrite

    unsigned short* Pw = sh + 35328 + p * 4224;    // per-PAIR [16][264]

#pragma unroll
    for (int it2 = 0; it2 < 2; it2++) {
        const int tt  = it2 ? tB : tA;
        const bf16x8 aq0 = it2 ? qB0 : qA0;
        const bf16x8 aq1 = it2 ? qB1 : qA1;
        const int nst = tt + 1;

        // E via MFMA vs Rk: D[m=quad*4+r][n=c] = q_{t0+m} . relk_n  (n<4 valid)
        f32x4 e = zero;
        e = MFMA16(aq0, ld16(Rk + c * 64 + quad * 8), e);
        e = MFMA16(aq1, ld16(Rk + c * 64 + 32 + quad * 8), e);
        float ef[4][4];
#pragma unroll
        for (int r = 0; r < 4; r++)
#pragma unroll
            for (int n = 0; n < 4; n++)
                ef[r][n] = __shfl(e[r], (lane & 48) + n, 64);

        // score tiles of my parity -> exp -> P^ in LDS; partial row sums
        float l[4] = {0.f, 0.f, 0.f, 0.f};
#pragma unroll
        for (int st = 0; st < 16; st++) {
            if ((st & 1) == hi) {
                if (st < nst) {
                    const unsigned short* kp = ksh + (st * 16 + c) * 72 + quad * 8;
                    f32x4 s = zero;
                    s = MFMA16(aq0, ld16(kp), s);
                    s = MFMA16(aq1, ld16(kp + 32), s);
#pragma unroll
                    for (int r = 0; r < 4; r++) {
                        int tg = tt * 16 + quad * 4 + r;
                        int sg = st * 16 + c;
                        int d  = sg - tg;
                        float ee = (d <= -3) ? ef[r][0] : (d == -2) ? ef[r][1]
                                 : (d == -1) ? ef[r][2] : ef[r][3];
                        float pv = (d > 0) ? 0.f : __expf(0.125f * (s[r] + ee));
                        l[r] += pv;
                        Pw[(quad * 4 + r) * 264 + sg] = f2bf(pv);
                    }
                } else if (st == nst && (nst & 1)) {
                    // zero-pad the half-open MFMA k-tile (odd nst -> parity 1)
#pragma unroll
                    for (int r = 0; r < 4; r++)
                        Pw[(quad * 4 + r) * 264 + st * 16 + c] = 0;
                }
            }
        }
        // partial row-sum over the 16 c-lanes, then exchange across the pair
#pragma unroll
        for (int r = 0; r < 4; r++)
#pragma unroll
            for (int ofs = 1; ofs < 16; ofs <<= 1)
                l[r] += __shfl_xor(l[r], ofs, 64);
        if (c == 0) {
#pragma unroll
            for (int r = 0; r < 4; r++)
                lsum[(p * 2 + hi) * 16 + quad * 4 + r] = l[r];
        }
        __syncthreads();                       // lsum + partner's P^ visible
        float rl[4];
#pragma unroll
        for (int r = 0; r < 4; r++)
            rl[r] = 1.0f / (l[r] + lsum[(p * 2 + (1 - hi)) * 16 + quad * 4 + r]);

        // O = P^ @ V  for my 2 nt columns (A rows m=c from P; B = vT from LDS)
        f32x4 o[2];
        o[0] = zero; o[1] = zero;
        const int ksteps = (nst + 1) >> 1;
#pragma unroll
        for (int ks = 0; ks < 8; ks++) {
            if (ks < ksteps) {
                bf16x8 ap = ld16(Pw + c * 264 + ks * 32 + quad * 8);
#pragma unroll
                for (int i = 0; i < 2; i++) {
                    const int nt = hi * 2 + i;
                    bf16x8 bv = ld16(vTs + (nt * 16 + c) * 264 + ks * 32 + quad * 8);
                    o[i] = MFMA16(ap, bv, o[i]);
                }
            }
        }

        // epilogue: normalize + w2 band-probability identity + store my 2 nt
#pragma unroll
        for (int r = 0; r < 4; r++) {
            int tl = quad * 4 + r;
            int tg = tt * 16 + tl;
            float pa  = (tg >= 2) ? bf2f(Pw[tl * 264 + tg - 2]) * rl[r] : 0.f;
            float pb  = (tg >= 1) ? bf2f(Pw[tl * 264 + tg - 1]) * rl[r] : 0.f;
            float pcv = bf2f(Pw[tl * 264 + tg]) * rl[r];
#pragma unroll
            for (int i = 0; i < 2; i++) {
                const int nt = hi * 2 + i;
                float r0 = rv[0][i];
                float w2 = r0 + pa * (rv[1][i] - r0) + pb * (rv[2][i] - r0)
                              + pcv * (rv[3][i] - r0);
                out[(size_t)(b * 256 + tg) * 64 + nt * 16 + c] = o[i][r] * rl[r] + w2;
            }
        }
        __syncthreads();                       // P^/lsum reads done before reuse
    }
}

// ---------------------------------------------------------------------------
extern "C" void kernel_launch(void* const* d_in, const int* in_sizes, int n_in,
                              void* d_out, int out_size, void* d_ws, size_t ws_size,
                              hipStream_t stream) {
    const float* x    = (const float*)d_in[0];
    const float* Wq   = (const float*)d_in[1];
    const float* Wk   = (const float*)d_in[2];
    const float* Wv   = (const float*)d_in[3];
    const float* relk = (const float*)d_in[4];
    const float* relv = (const float*)d_in[5];
    float* out = (float*)d_out;

    char* ws = (char*)d_ws;
    unsigned short* Wt = (unsigned short*)(ws);              // 147456 B
    unsigned short* Rk = (unsigned short*)(ws + 147456);     // 2048 B

    (void)hipFuncSetAttribute((const void*)fused_kernel,
                              hipFuncAttributeMaxDynamicSharedMemorySize, 159744);

    prep_wt<<<292, 256, 0, stream>>>(Wq, Wk, Wv, relk, Wt, Rk);
    fused_kernel<<<256, 1024, 159744, stream>>>(x, Wt, Rk, relv, out);
}

// Round 4
// 194.405 us; speedup vs baseline: 1.0187x; 1.0110x over previous
//
#include <hip/hip_runtime.h>
#include <hip/hip_bf16.h>

// Problem: B=256, T=256, C=384, H=64, MAX_REL=3 (causal -> rel idx 0..3 only)
// Round 11: r8/r9/r10 (three different occupancy/VGPR configs) all sat at
// ~78 us -> binding constraint is the barrier-lockstep chunk pipeline, not
// registers (60 VGPR + 48 AGPR ~= 108 <= 128 budget; no spill). This round:
//   - W staged ONCE (whole 147 KB, [192][392] u16, r6-proven stride) at the
//     prologue; the 3-chunk phase-1 main loop has ZERO barriers -> waves
//     slide freely, x prefetch-by-1 streams at full HBM duty cycle.
//   - outputs ksh/vTs/qs written OVER the W region after one pre-epilogue
//     barrier (W fully consumed by then). 8 barriers total (was ~12), none
//     in the hot loop.
//   - phase 2 = r10 pair-split verbatim + PV accumulator chains split by
//     ks parity (dep distance 4 MFMAs >= MFMA latency).

typedef __attribute__((ext_vector_type(8))) __bf16 bf16x8;
typedef __attribute__((ext_vector_type(8))) short short8;
typedef __attribute__((ext_vector_type(4))) float f32x4;
typedef __attribute__((ext_vector_type(4))) int   i32x4;

#define MFMA16(A, B, C) __builtin_amdgcn_mfma_f32_16x16x32_bf16((A), (B), (C), 0, 0, 0)

__device__ __forceinline__ unsigned short f2bf(float f) {
    unsigned int u = __builtin_bit_cast(unsigned int, f);
    u = (u + 0x7FFFu + ((u >> 16) & 1u)) >> 16;   // RNE
    return (unsigned short)u;
}
__device__ __forceinline__ float bf2f(unsigned short s) {
    unsigned int u = ((unsigned int)s) << 16;
    return __builtin_bit_cast(float, u);
}
__device__ __forceinline__ bf16x8 ld16(const unsigned short* p) {
    return __builtin_bit_cast(bf16x8, *(const i32x4*)p);
}

// ---------------------------------------------------------------------------
// Kernel 0: Wt[3][64][384] bf16 (W^T) + Rk[16][64] bf16 (rel_k rows 0..3, rest 0)
// ---------------------------------------------------------------------------
__global__ void prep_wt(const float* __restrict__ Wq, const float* __restrict__ Wk,
                        const float* __restrict__ Wv, const float* __restrict__ relk,
                        unsigned short* __restrict__ Wt, unsigned short* __restrict__ Rk) {
    int i = blockIdx.x * 256 + threadIdx.x;
    if (i < 3 * 64 * 384) {
        int kk = i % 384;
        int h  = (i / 384) & 63;
        int w  = i / (384 * 64);
        const float* W = (w == 0) ? Wq : ((w == 1) ? Wk : Wv);
        Wt[i] = f2bf(W[kk * 64 + h]);
    } else if (i < 3 * 64 * 384 + 1024) {
        int j = i - 3 * 64 * 384;
        int n = j >> 6, h = j & 63;
        Rk[j] = (n < 4) ? f2bf(relk[n * 64 + h]) : (unsigned short)0;
    }
}

// ---------------------------------------------------------------------------
// Fused QKV + attention. One block per batch, 1024 threads (16 waves).
// LDS (u16 offsets; dynamic request 150528 B = 75264 u16):
//   phase 1: ws [192][392] @ 0          150528 B  (whole W^T, staged once)
//   phase 2 (overlays ws after pre-epilogue barrier):
//     ksh [256][72]  @ 0       36864 B
//     vTs [64][264]  @ 18432   33792 B
//     qs  [256][72]  @ 35328   36864 B  (freed after q-frag loads)
//     P(pair p) = 35328 + p*4224, [16][264]  (67584 B, overlays qs+beyond)
//     lsum (8 pairs x 2 x 16 f32) @ u16 69120  (1024 B, ends 69632 < 75264)
// ---------------------------------------------------------------------------
__global__ __launch_bounds__(1024)
__attribute__((amdgpu_waves_per_eu(4, 4)))
void fused_kernel(
        const float* __restrict__ x, const unsigned short* __restrict__ Wt,
        const unsigned short* __restrict__ Rk, const float* __restrict__ relv,
        float* __restrict__ out) {
    extern __shared__ unsigned short sh[];
    unsigned short* ws  = sh;                  // phase 1
    unsigned short* ksh = sh;                  // phase 2
    unsigned short* vTs = sh + 18432;
    unsigned short* qs  = sh + 35328;
    float* lsum = (float*)(sh + 69120);

    const int tid  = threadIdx.x;
    const int wave = tid >> 6;
    const int lane = tid & 63;
    const int c    = lane & 15;
    const int quad = lane >> 4;
    const int b    = blockIdx.x;

    const f32x4 zero = {0.f, 0.f, 0.f, 0.f};

    // =================== phase 1: QKV GEMM (barrier-free main loop) =========
    // wave owns rows wave*16 + c ; lane reads its row at cols quad*8..+7 per j
    const float* xbase = x + (size_t)(b * 256 + wave * 16 + c) * 384 + quad * 8;

    f32x4 aq[4], ak[4], av[4];
#pragma unroll
    for (int nt = 0; nt < 4; nt++) { aq[nt] = zero; ak[nt] = zero; av[nt] = zero; }

    // issue x chunk-0 loads FIRST (HBM long pole), then stage W under them
    f32x4 tmp[8];
#pragma unroll
    for (int j = 0; j < 4; j++) {
        tmp[2 * j]     = *(const f32x4*)(xbase + j * 32);
        tmp[2 * j + 1] = *(const f32x4*)(xbase + j * 32 + 4);
    }

    // stage ALL of W once: 9216 b128 pieces, 9 per thread (L2-hot)
#pragma unroll
    for (int it = 0; it < 9; it++) {
        int P_ = it * 1024 + tid;
        int r = P_ / 48, pc = P_ % 48;
        i32x4 d = *(const i32x4*)(Wt + r * 384 + pc * 8);
        *(i32x4*)(ws + r * 392 + pc * 8) = d;
    }
    __syncthreads();                           // W resident; the ONLY loop barrier

#pragma unroll
    for (int ck = 0; ck < 3; ck++) {
        // convert this chunk's x to bf16 A-frags (frees tmp for the prefetch)
        bf16x8 a[4];
#pragma unroll
        for (int j = 0; j < 4; j++) {
            short8 xs8;
#pragma unroll
            for (int e = 0; e < 4; e++) {
                xs8[e]     = (short)f2bf(tmp[2 * j][e]);
                xs8[4 + e] = (short)f2bf(tmp[2 * j + 1][e]);
            }
            a[j] = __builtin_bit_cast(bf16x8, xs8);
        }
        // prefetch next chunk's x; lands during the MFMA loop below
        if (ck < 2) {
#pragma unroll
            for (int j = 0; j < 4; j++) {
                const float* xp = xbase + (ck + 1) * 128 + j * 32;
                tmp[2 * j]     = *(const f32x4*)xp;
                tmp[2 * j + 1] = *(const f32x4*)(xp + 4);
            }
        }

        // 3 B-frag LDS loads feed 3 MFMAs per (j,nt); W resident all along
#pragma unroll
        for (int j = 0; j < 4; j++) {
            const int col = ck * 128 + j * 32 + quad * 8;
#pragma unroll
            for (int nt = 0; nt < 4; nt++) {
                bf16x8 bq = ld16(ws + (nt * 16 + c) * 392 + col);
                bf16x8 bk = ld16(ws + (64 + nt * 16 + c) * 392 + col);
                bf16x8 aw = ld16(ws + (128 + nt * 16 + c) * 392 + col);
                aq[nt] = MFMA16(a[j], bq, aq[nt]);   // D[t][h]
                ak[nt] = MFMA16(a[j], bk, ak[nt]);   // D[t][h]
                av[nt] = MFMA16(aw, a[j], av[nt]);   // D[h][t]
            }
        }
    }
    __syncthreads();                           // all W reads done -> may overwrite

    // epilogue into LDS (C/D layout: col=lane&15, row=quad*4+reg)
#pragma unroll
    for (int nt = 0; nt < 4; nt++)
#pragma unroll
        for (int r = 0; r < 4; r++) {
            int row = wave * 16 + quad * 4 + r;
            qs[row * 72 + nt * 16 + c]  = f2bf(aq[nt][r]);
            ksh[row * 72 + nt * 16 + c] = f2bf(ak[nt][r]);
            vTs[(nt * 16 + quad * 4 + r) * 264 + wave * 16 + c] = f2bf(av[nt][r]);
        }
    __syncthreads();                           // q/k/vT visible to all waves

    // =================== phase 2: attention from LDS ===================
    // pair p = wave&7 handles q-tiles {p, 15-p}; hi = wave>>3 is the pair half.
    // scores split by s-tile parity; PV + output split by nt (2 per wave).
    const int p  = wave & 7;
    const int hi = wave >> 3;
    const int tA = p, tB = 15 - p;

    bf16x8 qA0 = ld16(qs + (tA * 16 + c) * 72 + quad * 8);
    bf16x8 qA1 = ld16(qs + (tA * 16 + c) * 72 + 32 + quad * 8);
    bf16x8 qB0 = ld16(qs + (tB * 16 + c) * 72 + quad * 8);
    bf16x8 qB1 = ld16(qs + (tB * 16 + c) * 72 + 32 + quad * 8);
    float rv[4][2];
#pragma unroll
    for (int j = 0; j < 4; j++)
#pragma unroll
        for (int i = 0; i < 2; i++)
            rv[j][i] = relv[j * 64 + (hi * 2 + i) * 16 + c];
    __syncthreads();                           // qs reads done -> P may overwrite

    unsigned short* Pw = sh + 35328 + p * 4224;    // per-PAIR [16][264]

#pragma unroll
    for (int it2 = 0; it2 < 2; it2++) {
        const int tt  = it2 ? tB : tA;
        const bf16x8 aq0 = it2 ? qB0 : qA0;
        const bf16x8 aq1 = it2 ? qB1 : qA1;
        const int nst = tt + 1;

        // E via MFMA vs Rk: D[m=quad*4+r][n=c] = q_{t0+m} . relk_n  (n<4 valid)
        f32x4 e = zero;
        e = MFMA16(aq0, ld16(Rk + c * 64 + quad * 8), e);
        e = MFMA16(aq1, ld16(Rk + c * 64 + 32 + quad * 8), e);
        float ef[4][4];
#pragma unroll
        for (int r = 0; r < 4; r++)
#pragma unroll
            for (int n = 0; n < 4; n++)
                ef[r][n] = __shfl(e[r], (lane & 48) + n, 64);

        // score tiles of my parity -> exp -> P^ in LDS; partial row sums
        float l[4] = {0.f, 0.f, 0.f, 0.f};
#pragma unroll
        for (int st = 0; st < 16; st++) {
            if ((st & 1) == hi) {
                if (st < nst) {
                    const unsigned short* kp = ksh + (st * 16 + c) * 72 + quad * 8;
                    f32x4 s = zero;
                    s = MFMA16(aq0, ld16(kp), s);
                    s = MFMA16(aq1, ld16(kp + 32), s);
#pragma unroll
                    for (int r = 0; r < 4; r++) {
                        int tg = tt * 16 + quad * 4 + r;
                        int sg = st * 16 + c;
                        int d  = sg - tg;
                        float ee = (d <= -3) ? ef[r][0] : (d == -2) ? ef[r][1]
                                 : (d == -1) ? ef[r][2] : ef[r][3];
                        float pv = (d > 0) ? 0.f : __expf(0.125f * (s[r] + ee));
                        l[r] += pv;
                        Pw[(quad * 4 + r) * 264 + sg] = f2bf(pv);
                    }
                } else if (st == nst && (nst & 1)) {
                    // zero-pad the half-open MFMA k-tile (odd nst -> parity 1)
#pragma unroll
                    for (int r = 0; r < 4; r++)
                        Pw[(quad * 4 + r) * 264 + st * 16 + c] = 0;
                }
            }
        }
        // partial row-sum over the 16 c-lanes, then exchange across the pair
#pragma unroll
        for (int r = 0; r < 4; r++)
#pragma unroll
            for (int ofs = 1; ofs < 16; ofs <<= 1)
                l[r] += __shfl_xor(l[r], ofs, 64);
        if (c == 0) {
#pragma unroll
            for (int r = 0; r < 4; r++)
                lsum[(p * 2 + hi) * 16 + quad * 4 + r] = l[r];
        }
        __syncthreads();                       // lsum + partner's P^ visible
        float rl[4];
#pragma unroll
        for (int r = 0; r < 4; r++)
            rl[r] = 1.0f / (l[r] + lsum[(p * 2 + (1 - hi)) * 16 + quad * 4 + r]);

        // O = P^ @ V for my 2 nt columns; accumulator chains split by ks parity
        f32x4 o0[2], o1[2];
        o0[0] = zero; o0[1] = zero; o1[0] = zero; o1[1] = zero;
        const int ksteps = (nst + 1) >> 1;
#pragma unroll
        for (int ks = 0; ks < 8; ks++) {
            if (ks < ksteps) {
                bf16x8 ap = ld16(Pw + c * 264 + ks * 32 + quad * 8);
#pragma unroll
                for (int i = 0; i < 2; i++) {
                    const int nt = hi * 2 + i;
                    bf16x8 bv = ld16(vTs + (nt * 16 + c) * 264 + ks * 32 + quad * 8);
                    if (ks & 1) o1[i] = MFMA16(ap, bv, o1[i]);
                    else        o0[i] = MFMA16(ap, bv, o0[i]);
                }
            }
        }

        // epilogue: normalize + w2 band-probability identity + store my 2 nt
#pragma unroll
        for (int r = 0; r < 4; r++) {
            int tl = quad * 4 + r;
            int tg = tt * 16 + tl;
            float pa  = (tg >= 2) ? bf2f(Pw[tl * 264 + tg - 2]) * rl[r] : 0.f;
            float pb  = (tg >= 1) ? bf2f(Pw[tl * 264 + tg - 1]) * rl[r] : 0.f;
            float pcv = bf2f(Pw[tl * 264 + tg]) * rl[r];
#pragma unroll
            for (int i = 0; i < 2; i++) {
                const int nt = hi * 2 + i;
                float r0 = rv[0][i];
                float w2 = r0 + pa * (rv[1][i] - r0) + pb * (rv[2][i] - r0)
                              + pcv * (rv[3][i] - r0);
                out[(size_t)(b * 256 + tg) * 64 + nt * 16 + c]
                    = (o0[i][r] + o1[i][r]) * rl[r] + w2;
            }
        }
        __syncthreads();                       // P^/lsum reads done before reuse
    }
}

// ---------------------------------------------------------------------------
extern "C" void kernel_launch(void* const* d_in, const int* in_sizes, int n_in,
                              void* d_out, int out_size, void* d_ws, size_t ws_size,
                              hipStream_t stream) {
    const float* x    = (const float*)d_in[0];
    const float* Wq   = (const float*)d_in[1];
    const float* Wk   = (const float*)d_in[2];
    const float* Wv   = (const float*)d_in[3];
    const float* relk = (const float*)d_in[4];
    const float* relv = (const float*)d_in[5];
    float* out = (float*)d_out;

    char* ws = (char*)d_ws;
    unsigned short* Wt = (unsigned short*)(ws);              // 147456 B
    unsigned short* Rk = (unsigned short*)(ws + 147456);     // 2048 B

    (void)hipFuncSetAttribute((const void*)fused_kernel,
                              hipFuncAttributeMaxDynamicSharedMemorySize, 150528);

    prep_wt<<<292, 256, 0, stream>>>(Wq, Wk, Wv, relk, Wt, Rk);
    fused_kernel<<<256, 1024, 150528, stream>>>(x, Wt, Rk, relv, out);
}